// Round 4
// baseline (230.288 us; speedup 1.0000x reference)
//
#include <hip/hip_runtime.h>
#include <hip/hip_bf16.h>

// GraphNodeEdgeConvolution: N=2048, K=8, FN=16, O=32
// Inputs fp32 (confirmed R1/R2/R3 forensics), output fp32 (R2/R3 error was
// exactly the bf16-packed-into-fp32 signature). Inputs bound BY SIZE.
constexpr int CN  = 2048;
constexpr int CK  = 8;
constexpr int CFN = 16;
constexpr int CO  = 32;

constexpr int JTILE  = 256;
constexpr int NJT    = CN / JTILE;     // 8
constexpr int CHUNK  = 32;
constexpr int NCHUNK = CN / CHUNK;     // 64 -> grid 8x64 = 512 blocks

// Kernel 1: rinv[i] = 1/sum_j adj[i,j] (0 if non-finite)
__global__ __launch_bounds__(256) void rowsum_k(const float* __restrict__ adj,
                                                float* __restrict__ rinv) {
    const int i = blockIdx.x;
    const int t = threadIdx.x;
    const float4* row = (const float4*)(adj + (size_t)i * CN);  // 512 float4
    float4 v0 = row[t], v1 = row[t + 256];
    float s = v0.x + v0.y + v0.z + v0.w + v1.x + v1.y + v1.z + v1.w;
    #pragma unroll
    for (int off = 32; off > 0; off >>= 1) s += __shfl_down(s, off, 64);
    __shared__ float partial[4];
    if ((t & 63) == 0) partial[t >> 6] = s;
    __syncthreads();
    if (t == 0) {
        float tot = partial[0] + partial[1] + partial[2] + partial[3];
        float r = 1.0f / tot;
        if (!isfinite(r)) r = 0.0f;
        rinv[i] = r;
    }
}

// Kernel 2: agg[j][k] += sum_i rinv[i]*adj[i,j]*E[i,j,k]; col[j] += sum_i rinv[i]*adj[i,j]
__global__ __launch_bounds__(256) void main_k(const float* __restrict__ E,
                                              const float* __restrict__ adj,
                                              const float* __restrict__ rinv,
                                              float* __restrict__ agg,   // [N][K] fp32
                                              float* __restrict__ col) { // [N] fp32
    const int j  = blockIdx.x * JTILE + threadIdx.x;
    const int i0 = blockIdx.y * CHUNK;

    float acc[CK];
    #pragma unroll
    for (int k = 0; k < CK; ++k) acc[k] = 0.f;
    float colacc = 0.f;

    #pragma unroll 4
    for (int ii = 0; ii < CHUNK; ++ii) {
        const int i = i0 + ii;
        const float a = rinv[i] * adj[(size_t)i * CN + j];
        const float4* ev = (const float4*)(E + ((size_t)i * CN + j) * CK); // 32B, coalesced
        const float4 e0 = ev[0];
        const float4 e1 = ev[1];
        acc[0] += a * e0.x; acc[1] += a * e0.y;
        acc[2] += a * e0.z; acc[3] += a * e0.w;
        acc[4] += a * e1.x; acc[5] += a * e1.y;
        acc[6] += a * e1.z; acc[7] += a * e1.w;
        colacc += a;
    }

    float* aj = agg + (size_t)j * CK;
    #pragma unroll
    for (int k = 0; k < CK; ++k) atomicAdd(aj + k, acc[k]);
    atomicAdd(col + j, colacc);
}

// Kernel 3: out[j,o] = sum_k agg[j,k]*W[k,o] + col[j]*sum_f NF[j,f]*W[8+f,o]
__global__ __launch_bounds__(256) void epilogue_k(const float* __restrict__ agg,
                                                  const float* __restrict__ col,
                                                  const float* __restrict__ nf,
                                                  const float* __restrict__ wt,
                                                  float* __restrict__ out) {
    const int gid = blockIdx.x * 256 + threadIdx.x;   // 0 .. N*O-1
    const int j = gid >> 5;
    const int o = gid & 31;
    float s1 = 0.f;
    #pragma unroll
    for (int k = 0; k < CK; ++k)
        s1 += agg[(size_t)j * CK + k] * wt[k * CO + o];
    float s2 = 0.f;
    #pragma unroll
    for (int f = 0; f < CFN; ++f)
        s2 += nf[(size_t)j * CFN + f] * wt[(CK + f) * CO + o];
    out[gid] = s1 + col[j] * s2;   // fp32 output
}

extern "C" void kernel_launch(void* const* d_in, const int* in_sizes, int n_in,
                              void* d_out, int out_size, void* d_ws, size_t ws_size,
                              hipStream_t stream) {
    // Bind inputs BY ELEMENT COUNT (all four counts distinct).
    const float *nf = nullptr, *E = nullptr, *adj = nullptr, *wt = nullptr;
    for (int i = 0; i < n_in; ++i) {
        switch (in_sizes[i]) {
            case CN * CFN:        nf  = (const float*)d_in[i]; break;  // 32768
            case CN * CN * CK:    E   = (const float*)d_in[i]; break;  // 33554432
            case CN * CN:         adj = (const float*)d_in[i]; break;  // 4194304
            case (CK + CFN) * CO: wt  = (const float*)d_in[i]; break;  // 768
        }
    }
    float* out = (float*)d_out;

    // ws (fp32): rinv[2048] | agg[2048*8] | col[2048]  = 80 KiB
    float* rinv = (float*)d_ws;
    float* agg  = rinv + CN;
    float* col  = agg + (size_t)CN * CK;
    size_t zero_bytes = (size_t)(CN + CN * CK + CN) * sizeof(float);
    hipMemsetAsync(d_ws, 0, zero_bytes, stream);

    rowsum_k<<<CN, 256, 0, stream>>>(adj, rinv);
    main_k<<<dim3(NJT, NCHUNK), 256, 0, stream>>>(E, adj, rinv, agg, col);
    epilogue_k<<<(CN * CO) / 256, 256, 0, stream>>>(agg, col, nf, wt, out);
}

// Round 5
// 215.244 us; speedup vs baseline: 1.0699x; 1.0699x over previous
//
#include <hip/hip_runtime.h>
#include <hip/hip_bf16.h>

// GraphNodeEdgeConvolution: N=2048, K=8, FN=16, O=32
// fp32 in / fp32 out (R0-R4 forensics). Inputs bound BY SIZE.
// R5: atomics -> two-pass deterministic reduction (cross-XCD atomic
// contention was the prime suspect for 230us vs ~35us roofline).
constexpr int CN  = 2048;
constexpr int CK  = 8;
constexpr int CFN = 16;
constexpr int CO  = 32;

constexpr int JTILE  = 256;
constexpr int NJT    = CN / JTILE;     // 8
constexpr int CHUNK  = 32;
constexpr int NCHUNK = CN / CHUNK;     // 64 -> grid 8x64 = 512 blocks
constexpr int NACC   = CK + 1;         // 8 agg planes + 1 colsum plane

// Kernel 1: rinv[i] = 1/sum_j adj[i,j] (0 if non-finite)
__global__ __launch_bounds__(256) void rowsum_k(const float* __restrict__ adj,
                                                float* __restrict__ rinv) {
    const int i = blockIdx.x;
    const int t = threadIdx.x;
    const float4* row = (const float4*)(adj + (size_t)i * CN);  // 512 float4
    float4 v0 = row[t], v1 = row[t + 256];
    float s = v0.x + v0.y + v0.z + v0.w + v1.x + v1.y + v1.z + v1.w;
    #pragma unroll
    for (int off = 32; off > 0; off >>= 1) s += __shfl_down(s, off, 64);
    __shared__ float partial[4];
    if ((t & 63) == 0) partial[t >> 6] = s;
    __syncthreads();
    if (t == 0) {
        float tot = partial[0] + partial[1] + partial[2] + partial[3];
        float r = 1.0f / tot;
        if (!isfinite(r)) r = 0.0f;
        rinv[i] = r;
    }
}

// Kernel 2: stream E; per-thread j-column accumulators over a 32-row i-chunk;
// store partials to plane-major layout part[k][ic][j] (coalesced, no atomics).
__global__ __launch_bounds__(256) void main_k(const float* __restrict__ E,
                                              const float* __restrict__ adj,
                                              const float* __restrict__ rinv,
                                              float* __restrict__ part) {
    const int t  = threadIdx.x;
    const int j  = blockIdx.x * JTILE + t;
    const int ic = blockIdx.y;
    const int i0 = ic * CHUNK;

    float acc[NACC];
    #pragma unroll
    for (int k = 0; k < NACC; ++k) acc[k] = 0.f;

    #pragma unroll 4
    for (int ii = 0; ii < CHUNK; ++ii) {
        const int i = i0 + ii;
        const float a = rinv[i] * adj[(size_t)i * CN + j];
        const float4* ev = (const float4*)(E + ((size_t)i * CN + j) * CK); // 32B/lane
        const float4 e0 = ev[0];
        const float4 e1 = ev[1];
        acc[0] += a * e0.x; acc[1] += a * e0.y;
        acc[2] += a * e0.z; acc[3] += a * e0.w;
        acc[4] += a * e1.x; acc[5] += a * e1.y;
        acc[6] += a * e1.z; acc[7] += a * e1.w;
        acc[8] += a;
    }

    #pragma unroll
    for (int k = 0; k < NACC; ++k)
        part[(size_t)k * (NCHUNK * CN) + (size_t)ic * CN + j] = acc[k];
}

// Kernel 3: reduce 64 chunks -> aggT[k][j] (k=8 plane is colsum)
__global__ __launch_bounds__(256) void reduce_k(const float* __restrict__ part,
                                                float* __restrict__ aggT) {
    const int gid = blockIdx.x * 256 + threadIdx.x;   // 0 .. 9*2048-1
    const int k = gid >> 11;         // gid / 2048
    const int j = gid & (CN - 1);
    const float* p = part + (size_t)k * (NCHUNK * CN) + j;
    float s = 0.f;
    #pragma unroll 8
    for (int ic = 0; ic < NCHUNK; ++ic) s += p[(size_t)ic * CN];
    aggT[gid] = s;
}

// Kernel 4: out[j,o] = sum_k aggT[k][j]*W[k,o] + col[j]*sum_f NF[j,f]*W[8+f,o]
__global__ __launch_bounds__(256) void epilogue_k(const float* __restrict__ aggT,
                                                  const float* __restrict__ nf,
                                                  const float* __restrict__ wt,
                                                  float* __restrict__ out) {
    const int gid = blockIdx.x * 256 + threadIdx.x;   // 0 .. N*O-1
    const int j = gid >> 5;
    const int o = gid & 31;
    float s1 = 0.f;
    #pragma unroll
    for (int k = 0; k < CK; ++k)
        s1 += aggT[(size_t)k * CN + j] * wt[k * CO + o];
    float s2 = 0.f;
    #pragma unroll
    for (int f = 0; f < CFN; ++f)
        s2 += nf[(size_t)j * CFN + f] * wt[(CK + f) * CO + o];
    out[gid] = s1 + aggT[(size_t)CK * CN + j] * s2;   // fp32 output
}

extern "C" void kernel_launch(void* const* d_in, const int* in_sizes, int n_in,
                              void* d_out, int out_size, void* d_ws, size_t ws_size,
                              hipStream_t stream) {
    // Bind inputs BY ELEMENT COUNT (all four counts distinct).
    const float *nf = nullptr, *E = nullptr, *adj = nullptr, *wt = nullptr;
    for (int i = 0; i < n_in; ++i) {
        switch (in_sizes[i]) {
            case CN * CFN:        nf  = (const float*)d_in[i]; break;  // 32768
            case CN * CN * CK:    E   = (const float*)d_in[i]; break;  // 33554432
            case CN * CN:         adj = (const float*)d_in[i]; break;  // 4194304
            case (CK + CFN) * CO: wt  = (const float*)d_in[i]; break;  // 768
        }
    }
    float* out = (float*)d_out;

    // ws (fp32): rinv[2048] | part[9*64*2048] | aggT[9*2048]
    // Every ws word consumed is written first by a prior kernel -> no memset.
    float* rinv = (float*)d_ws;
    float* part = rinv + CN;
    float* aggT = part + (size_t)NACC * NCHUNK * CN;

    rowsum_k<<<CN, 256, 0, stream>>>(adj, rinv);
    main_k<<<dim3(NJT, NCHUNK), 256, 0, stream>>>(E, adj, rinv, part);
    reduce_k<<<(NACC * CN) / 256, 256, 0, stream>>>(part, aggT);
    epilogue_k<<<(CN * CO) / 256, 256, 0, stream>>>(aggT, nf, wt, out);
}